// Round 2
// baseline (608.152 us; speedup 1.0000x reference)
//
#include <hip/hip_runtime.h>
#include <hip/hip_bf16.h>

#define VOCAB 1000000
#define EMB 128
#define NEG 512
#define BATCH 16384

#define BM 64
#define BN 64
#define KE 160          // 128 real K + 32 ext slots (const folded into GEMM)
#define LDSTR 168       // LDS row stride in bf16 elems: 336B, 16B-aligned, 2-way-bank-free

#define NMAIN ((BATCH / BM) * (NEG / BN))   // 2048
#define NTRUE_BLK (BATCH / 4)               // 4096 (4 rows per block, wave-per-row)
#define NPART (NMAIN + NTRUE_BLK)           // 6144

typedef __attribute__((ext_vector_type(8))) short bf16x8;
typedef __attribute__((ext_vector_type(4))) float f32x4;

static __device__ __forceinline__ unsigned short f2bf(float f) {
    union { __hip_bfloat16 b; unsigned short u; } cv;
    cv.b = __float2bfloat16(f);
    return cv.u;
}
static __device__ __forceinline__ float bf2f(unsigned short u) {
    union { unsigned short u; __hip_bfloat16 b; } cv;
    cv.u = u;
    return __bfloat162float(cv.b);
}

// -log(expected_count(c)) per TF LogUniformCandidateSampler.
// CRITICAL: p via log1p(1/(c+1)), NOT log(c+2)-log(c+1) — the latter
// cancels to 0 in fp32 for c ~ 1e6 (diff ~1e-6 vs ulp(13.8)=9.5e-7),
// giving E=0 -> -log(0)=inf -> inf-inf=NaN in the true-label path.
static __device__ __forceinline__ float neg_log_expected(int c) {
    float cf = (float)c;
    float p = log1pf(1.0f / (cf + 1.0f)) / logf((float)VOCAB + 1.0f);
    float E = -expm1f((float)NEG * log1pf(-p));
    return -logf(E);
}

// Gather sampled weight rows -> bf16, append ext slots:
// slot128 = c_hi, slot129 = c_lo (2-way bf16 split of bias - log(E)), 130..159 = 0
__global__ __launch_bounds__(64) void prep_k(const float* __restrict__ weights,
                                             const float* __restrict__ biases,
                                             const int* __restrict__ sampled,
                                             unsigned short* __restrict__ swe) {
    int s = blockIdx.x;
    int t = threadIdx.x;
    int sid = sampled[s];
    unsigned short* row = swe + (size_t)s * KE;
    if (t < 32) {
        const float4* src = (const float4*)(weights + (size_t)sid * EMB);
        float4 v = src[t];
        uint2 p;
        p.x = (unsigned)f2bf(v.x) | ((unsigned)f2bf(v.y) << 16);
        p.y = (unsigned)f2bf(v.z) | ((unsigned)f2bf(v.w) << 16);
        *(uint2*)(row + t * 4) = p;
    } else {
        int slot = 128 + (t - 32);
        unsigned short v = 0;
        if (slot <= 129) {
            float c = biases[sid] + neg_log_expected(sid);
            unsigned short hi = f2bf(c);
            v = (slot == 128) ? hi : f2bf(c - bf2f(hi));
        }
        row[slot] = v;
    }
}

__global__ __launch_bounds__(256) void main_k(const float* __restrict__ pred,
                                              const float* __restrict__ weights,
                                              const float* __restrict__ biases,
                                              const int* __restrict__ labels,
                                              const unsigned short* __restrict__ swe,
                                              float* __restrict__ partials) {
    __shared__ unsigned short As[BM * LDSTR];
    __shared__ unsigned short Bs[BN * LDSTR];
    __shared__ float red[4];
    int bid = blockIdx.x;
    int tid = threadIdx.x;
    int lane = tid & 63;
    int wv = tid >> 6;

    if (bid < NMAIN) {
        // ---- sampled-logits GEMM tile: 64 rows x 64 samples ----
        int m0 = (bid >> 3) * BM;
        int s0 = (bid & 7) * BN;

        // stage A (pred rows, fp32 -> bf16), k-contiguous
        const float4* pred4 = (const float4*)pred;
#pragma unroll
        for (int i = 0; i < 8; ++i) {
            int l = tid + i * 256;
            int row = l >> 5, k4 = l & 31;
            float4 v = pred4[(size_t)(m0 + row) * 32 + k4];
            uint2 p;
            p.x = (unsigned)f2bf(v.x) | ((unsigned)f2bf(v.y) << 16);
            p.y = (unsigned)f2bf(v.z) | ((unsigned)f2bf(v.w) << 16);
            *(uint2*)&As[row * LDSTR + k4 * 4] = p;
        }
        // stage A ext slots: [128]=[129]=1.0 (bf16 0x3F80), rest 0
#pragma unroll
        for (int i = 0; i < 8; ++i) {
            int l = tid + i * 256;
            int row = l >> 5, sl = l & 31;
            As[row * LDSTR + 128 + sl] = (sl < 2) ? (unsigned short)0x3F80 : (unsigned short)0;
        }
        // stage B (prepped bf16 rows incl. ext): 160 ushorts = 40 uint2 per row
#pragma unroll
        for (int i = 0; i < 10; ++i) {
            int l = tid + i * 256;
            int row = l / 40, j = l % 40;
            uint2 p = ((const uint2*)(swe + (size_t)(s0 + row) * KE))[j];
            *(uint2*)&Bs[row * LDSTR + j * 4] = p;
        }
        __syncthreads();

        int wm = (wv & 1) * 32;
        int wn = (wv >> 1) * 32;
        int fr = lane & 15;
        int kq = (lane >> 4) * 8;

        f32x4 zero = {0.0f, 0.0f, 0.0f, 0.0f};
        f32x4 acc00 = zero, acc01 = zero, acc10 = zero, acc11 = zero;
#pragma unroll
        for (int kc = 0; kc < KE; kc += 32) {
            int kk = kc + kq;
            bf16x8 a0 = *(const bf16x8*)&As[(wm + fr) * LDSTR + kk];
            bf16x8 a1 = *(const bf16x8*)&As[(wm + 16 + fr) * LDSTR + kk];
            bf16x8 b0 = *(const bf16x8*)&Bs[(wn + fr) * LDSTR + kk];
            bf16x8 b1 = *(const bf16x8*)&Bs[(wn + 16 + fr) * LDSTR + kk];
            acc00 = __builtin_amdgcn_mfma_f32_16x16x32_bf16(a0, b0, acc00, 0, 0, 0);
            acc01 = __builtin_amdgcn_mfma_f32_16x16x32_bf16(a0, b1, acc01, 0, 0, 0);
            acc10 = __builtin_amdgcn_mfma_f32_16x16x32_bf16(a1, b0, acc10, 0, 0, 0);
            acc11 = __builtin_amdgcn_mfma_f32_16x16x32_bf16(a1, b1, acc11, 0, 0, 0);
        }
        // every acc element is a finished sampled logit (const baked in via K-ext)
        float loss = 0.0f;
#pragma unroll
        for (int r = 0; r < 4; ++r) {
            float x;
            x = acc00[r]; loss += fmaxf(x, 0.0f) + log1pf(expf(-fabsf(x)));
            x = acc01[r]; loss += fmaxf(x, 0.0f) + log1pf(expf(-fabsf(x)));
            x = acc10[r]; loss += fmaxf(x, 0.0f) + log1pf(expf(-fabsf(x)));
            x = acc11[r]; loss += fmaxf(x, 0.0f) + log1pf(expf(-fabsf(x)));
        }
#pragma unroll
        for (int off = 32; off > 0; off >>= 1) loss += __shfl_xor(loss, off);
        if (lane == 0) red[wv] = loss;
        __syncthreads();
        if (tid == 0) partials[bid] = red[0] + red[1] + red[2] + red[3];
    } else {
        // ---- true-label path: wave-per-row, fp32 exact ----
        int b = (bid - NMAIN) * 4 + wv;
        int lbl = labels[b];
        float2 a = ((const float2*)pred)[(size_t)b * 64 + lane];
        float2 w = ((const float2*)weights)[(size_t)lbl * 64 + lane];
        float dot = a.x * w.x + a.y * w.y;
#pragma unroll
        for (int off = 32; off > 0; off >>= 1) dot += __shfl_xor(dot, off);
        if (lane == 0) {
            float x = dot + biases[lbl] + neg_log_expected(lbl);
            // sigmoid CE with z = 1/NTRUE = 1
            red[wv] = fmaxf(x, 0.0f) - x + log1pf(expf(-fabsf(x)));
        }
        __syncthreads();
        if (tid == 0) partials[bid] = red[0] + red[1] + red[2] + red[3];
    }
}

__global__ __launch_bounds__(256) void reduce_k(const float* __restrict__ partials,
                                                float* __restrict__ out) {
    int tid = threadIdx.x;
    float s = 0.0f;
    for (int i = tid; i < NPART; i += 256) s += partials[i];
#pragma unroll
    for (int off = 32; off > 0; off >>= 1) s += __shfl_xor(s, off);
    __shared__ float r[4];
    if ((tid & 63) == 0) r[tid >> 6] = s;
    __syncthreads();
    if (tid == 0) out[0] = (r[0] + r[1] + r[2] + r[3]) * (1.0f / (float)BATCH);
}

extern "C" void kernel_launch(void* const* d_in, const int* in_sizes, int n_in,
                              void* d_out, int out_size, void* d_ws, size_t ws_size,
                              hipStream_t stream) {
    const float* pred    = (const float*)d_in[0];
    const float* weights = (const float*)d_in[1];
    const float* biases  = (const float*)d_in[2];
    const int*   labels  = (const int*)d_in[3];
    const int*   sampled = (const int*)d_in[4];

    unsigned short* swe = (unsigned short*)d_ws;
    float* partials = (float*)((char*)d_ws + (size_t)NEG * KE * sizeof(unsigned short));
    float* out = (float*)d_out;

    prep_k<<<dim3(NEG), dim3(64), 0, stream>>>(weights, biases, sampled, swe);
    main_k<<<dim3(NPART), dim3(256), 0, stream>>>(pred, weights, biases, labels, swe, partials);
    reduce_k<<<dim3(1), dim3(256), 0, stream>>>(partials, out);
}